// Round 11
// baseline (312.051 us; speedup 1.0000x reference)
//
#include <hip/hip_runtime.h>
#include <math.h>

#define DHYP 64
#define DSPH 32
#define DEUC 32
#define DTOT 128
#define GAMMA_C 12.0f
#define EPS_C 1e-6f

typedef __attribute__((ext_vector_type(8))) __bf16 bf16x8;
typedef __attribute__((ext_vector_type(4))) float f32x4;

__device__ __forceinline__ float wsum64(float x) {
#pragma unroll
  for (int off = 1; off < 64; off <<= 1) x += __shfl_xor(x, off);
  return x;
}

// ---------------------------------------------------------------------------
// Kernel 1a: wave-per-row translate. Lane k holds dim k (hyperbolic) and
// dim 64+k (sphere for lanes 0..31, euclid for lanes 32..63).
// Emits plain fp32 q-rows (sign folded into q[0]) + te2v.
// ---------------------------------------------------------------------------
__global__ void rie_translate(const int* __restrict__ h_ids,
                              const int* __restrict__ r_ids,
                              const float* __restrict__ ent,
                              const float* __restrict__ rel,
                              float* __restrict__ qrows,
                              float* __restrict__ te2v, int B) {
  const int lane = threadIdx.x & 63;
  const int wave = threadIdx.x >> 6;
  const int b = blockIdx.x * (blockDim.x >> 6) + wave;
  if (b >= B) return;

  const float* __restrict__ h = ent + (long long)h_ids[b] * DTOT;
  const float* __restrict__ r = rel + (long long)r_ids[b] * DTOT;
  const float h1 = h[lane], h2 = h[64 + lane];
  const float r1 = r[lane], r2 = r[64 + lane];

  // ---- hyperbolic (dims 0..63; lane k = dim k) ----
  float ip = wsum64(lane == 0 ? -h1 * r1 : h1 * r1);  // minkowski(h,r)
  float v = fmaf(ip, h1, r1);                          // vh
  float mvv = wsum64(lane == 0 ? -v * v : v * v);      // minkowski(v,v)
  float vn = sqrtf(fmaxf(mvv, EPS_C));
  float ch = coshf(vn);
  float sh = sinhf(vn) / vn;
  float th = ch * h1 + sh * v;
  float q1 = (lane == 0) ? -th : th;  // fold Minkowski sign into query

  // ---- second half: sphere (lanes 0..31), euclid (lanes 32..63) ----
  const bool is_s = lane < 32;
  float ips = wsum64(is_s ? h2 * r2 : 0.0f);
  float vs = fmaf(-ips, h2, r2);
  float nv = wsum64(is_s ? vs * vs : 0.0f);
  float vns = fmaxf(sqrtf(nv), EPS_C);
  float cs = cosf(vns);
  float sn = sinf(vns) / vns;
  float ts = cs * h2 + sn * vs;

  float te = h2 + r2;
  float te2 = wsum64(is_s ? 0.0f : te * te);
  float q2 = is_s ? ts : te;

  qrows[b * DTOT + lane] = q1;
  qrows[b * DTOT + 64 + lane] = q2;
  if (lane == 0) te2v[b] = te2;
}

// ---------------------------------------------------------------------------
// Kernel 1b: repack q-rows into split-bf16 MFMA A-fragment tables.
// tab[(c*4+mt)*64 + g*16 + lmod] holds row (mt*16+lmod), k = 32c+8g..+8
// (m89-verified A layout); Al at +1024 entries (contiguous 32 KB total).
// ---------------------------------------------------------------------------
__global__ void rie_pack_frags(const float* __restrict__ qrows,
                               bf16x8* __restrict__ ah_tab,
                               bf16x8* __restrict__ al_tab) {
  const int t = threadIdx.x;
#pragma unroll
  for (int i = 0; i < 4; ++i) {
    const int idx = t + i * 256;
    const int cmt = idx >> 6;     // c*4 + mt
    const int c = cmt >> 2;
    const int mt = cmt & 3;
    const int lane = idx & 63;
    const int lmod = lane & 15;
    const int g = lane >> 4;
    const int row = mt * 16 + lmod;
    const int k0 = 32 * c + 8 * g;
    const float* __restrict__ src = qrows + row * DTOT + k0;
    const f32x4 a = *reinterpret_cast<const f32x4*>(src);
    const f32x4 bb = *reinterpret_cast<const f32x4*>(src + 4);
    bf16x8 Ah, Al;
#pragma unroll
    for (int j = 0; j < 4; ++j) {
      float x = a[j];
      __bf16 hx = (__bf16)x;
      Ah[j] = hx;
      Al[j] = (__bf16)(x - (float)hx);
      float y = bb[j];
      __bf16 hy = (__bf16)y;
      Ah[j + 4] = hy;
      Al[j + 4] = (__bf16)(y - (float)hy);
    }
    ah_tab[idx] = Ah;
    al_tab[idx] = Al;
  }
}

// ---------------------------------------------------------------------------
// Fast transcendentals (abs err ~7e-5, threshold headroom ~0.19)
// ---------------------------------------------------------------------------
__device__ __forceinline__ float fast_acos(float x) {
  float ax = fabsf(x);
  float p = fmaf(ax, -0.0187293f, 0.0742610f);
  p = fmaf(p, ax, -0.2121144f);
  p = fmaf(p, ax, 1.5707288f);
  float r = sqrtf(fmaxf(1.0f - ax, 0.0f)) * p;
  return (x < 0.0f) ? (3.14159265358979f - r) : r;
}

__device__ __forceinline__ float fast_acosh(float x) {
  // x >= 1. fma(x,x,-1) keeps full product precision near x=1.
  float t = x + sqrtf(fmaxf(fmaf(x, x, -1.0f), 0.0f));
  return 0.69314718055995f * __log2f(t);
}

// ---------------------------------------------------------------------------
// Kernel 2: split-bf16 MFMA distance GEMM, grid-stride over 64-entity tiles.
// A-table staged in LDS ONCE per block (32 KB), then no further barriers —
// iterations free-run so loads of tile t+1 overlap compute of tile t.
// Grid = 1280 blocks (5 blocks/CU x 256 CU at 32 KB LDS each = 160 KB).
// ---------------------------------------------------------------------------
__device__ __forceinline__ void split8(const f32x4& lo, const f32x4& hi,
                                       bf16x8& Bh, bf16x8& Bl) {
#pragma unroll
  for (int j = 0; j < 4; ++j) {
    float x = lo[j];
    __bf16 hx = (__bf16)x;
    Bh[j] = hx;
    Bl[j] = (__bf16)(x - (float)hx);
    float y = hi[j];
    __bf16 hy = (__bf16)y;
    Bh[j + 4] = hy;
    Bl[j + 4] = (__bf16)(y - (float)hy);
  }
}

__device__ __forceinline__ void mt_step(const bf16x8* tab_lds, int base,
                                        const bf16x8& Bh, const bf16x8& Bl,
                                        f32x4& acc) {
  bf16x8 Ah = tab_lds[base];          // ds_read_b128
  bf16x8 Al = tab_lds[base + 1024];   // ds_read_b128 (Al half)
  acc = __builtin_amdgcn_mfma_f32_16x16x32_bf16(Ah, Bh, acc, 0, 0, 0);
  acc = __builtin_amdgcn_mfma_f32_16x16x32_bf16(Al, Bh, acc, 0, 0, 0);
  acc = __builtin_amdgcn_mfma_f32_16x16x32_bf16(Ah, Bl, acc, 0, 0, 0);
}

__global__ __launch_bounds__(256, 4) void rie_dist_mfma(
    const float* __restrict__ ent, const bf16x8* __restrict__ ah_tab,
    const float* __restrict__ te2v, float* __restrict__ out, int E,
    int ntiles) {
  __shared__ bf16x8 tab_lds[2048];  // 32 KB: [0..1023]=Ah, [1024..2047]=Al

  const int lane = threadIdx.x & 63;
  const int wave = threadIdx.x >> 6;
  const int lmod = lane & 15;
  const int lgrp = lane >> 4;

  // ---- one-time cooperative copy of the 32 KB A-table into LDS ----
#pragma unroll
  for (int j = 0; j < 8; ++j)
    tab_lds[threadIdx.x + j * 256] = ah_tab[threadIdx.x + j * 256];
  __syncthreads();  // the ONLY barrier; iterations below free-run

  for (int t = blockIdx.x; t < ntiles; t += gridDim.x) {
    const int e0 = t * 64 + wave * 16;

    const float* __restrict__ erow =
        ent + (long long)(e0 + lmod) * DTOT + 8 * lgrp;
    f32x4 b0a = *reinterpret_cast<const f32x4*>(erow);
    f32x4 b0b = *reinterpret_cast<const f32x4*>(erow + 4);
    f32x4 b1a = *reinterpret_cast<const f32x4*>(erow + 32);
    f32x4 b1b = *reinterpret_cast<const f32x4*>(erow + 36);
    f32x4 b2a = *reinterpret_cast<const f32x4*>(erow + 64);
    f32x4 b2b = *reinterpret_cast<const f32x4*>(erow + 68);
    f32x4 b3a = *reinterpret_cast<const f32x4*>(erow + 96);
    f32x4 b3b = *reinterpret_cast<const f32x4*>(erow + 100);

    // ---- |ee|^2 of this lane's entity ----
    float ee2 = 0.0f;
#pragma unroll
    for (int j = 0; j < 4; ++j) {
      ee2 = fmaf(b3a[j], b3a[j], ee2);
      ee2 = fmaf(b3b[j], b3b[j], ee2);
    }
    ee2 += __shfl_xor(ee2, 16);
    ee2 += __shfl_xor(ee2, 32);

    const f32x4 z = {0.f, 0.f, 0.f, 0.f};
    f32x4 aH0 = z, aH1 = z, aH2 = z, aH3 = z;
    f32x4 aS0 = z, aS1 = z, aS2 = z, aS3 = z;
    f32x4 aE0 = z, aE1 = z, aE2 = z, aE3 = z;

    {  // chunk 0 (k 0..31, hyperbolic)
      bf16x8 Bh, Bl;
      split8(b0a, b0b, Bh, Bl);
      mt_step(tab_lds, (0 * 4 + 0) * 64 + lane, Bh, Bl, aH0);
      mt_step(tab_lds, (0 * 4 + 1) * 64 + lane, Bh, Bl, aH1);
      mt_step(tab_lds, (0 * 4 + 2) * 64 + lane, Bh, Bl, aH2);
      mt_step(tab_lds, (0 * 4 + 3) * 64 + lane, Bh, Bl, aH3);
    }
    {  // chunk 1 (k 32..63, hyperbolic)
      bf16x8 Bh, Bl;
      split8(b1a, b1b, Bh, Bl);
      mt_step(tab_lds, (1 * 4 + 0) * 64 + lane, Bh, Bl, aH0);
      mt_step(tab_lds, (1 * 4 + 1) * 64 + lane, Bh, Bl, aH1);
      mt_step(tab_lds, (1 * 4 + 2) * 64 + lane, Bh, Bl, aH2);
      mt_step(tab_lds, (1 * 4 + 3) * 64 + lane, Bh, Bl, aH3);
    }
    {  // chunk 2 (k 64..95, sphere)
      bf16x8 Bh, Bl;
      split8(b2a, b2b, Bh, Bl);
      mt_step(tab_lds, (2 * 4 + 0) * 64 + lane, Bh, Bl, aS0);
      mt_step(tab_lds, (2 * 4 + 1) * 64 + lane, Bh, Bl, aS1);
      mt_step(tab_lds, (2 * 4 + 2) * 64 + lane, Bh, Bl, aS2);
      mt_step(tab_lds, (2 * 4 + 3) * 64 + lane, Bh, Bl, aS3);
    }
    {  // chunk 3 (k 96..127, euclid)
      bf16x8 Bh, Bl;
      split8(b3a, b3b, Bh, Bl);
      mt_step(tab_lds, (3 * 4 + 0) * 64 + lane, Bh, Bl, aE0);
      mt_step(tab_lds, (3 * 4 + 1) * 64 + lane, Bh, Bl, aE1);
      mt_step(tab_lds, (3 * 4 + 2) * 64 + lane, Bh, Bl, aE2);
      mt_step(tab_lds, (3 * 4 + 3) * 64 + lane, Bh, Bl, aE3);
    }

    // ---- epilogue: fast transcendentals + store ----
#define EPI(MT, AH, AS, AE)                                                   \
  {                                                                           \
    const f32x4 t2 =                                                          \
        *reinterpret_cast<const f32x4*>(te2v + MT * 16 + 4 * lgrp);           \
    _Pragma("unroll") for (int r = 0; r < 4; ++r) {                           \
      float x = fmaxf(-AH[r], 1.0f + EPS_C);                                  \
      float dh = fast_acosh(x);                                               \
      float yv = fminf(fmaxf(AS[r], -1.0f + EPS_C), 1.0f - EPS_C);            \
      float dsv = fast_acos(yv);                                              \
      float de2 = fmaxf(t2[r] + ee2 - 2.0f * AE[r], 0.0f);                    \
      float dist = sqrtf(fmaf(dh, dh, fmaf(dsv, dsv, de2 + EPS_C)));          \
      out[(long long)(MT * 16 + 4 * lgrp + r) * E + e0 + lmod] =              \
          GAMMA_C - dist;                                                     \
    }                                                                         \
  }
    EPI(0, aH0, aS0, aE0);
    EPI(1, aH1, aS1, aE1);
    EPI(2, aH2, aS2, aE2);
    EPI(3, aH3, aS3, aE3);
#undef EPI
  }
}

// ---------------------------------------------------------------------------
extern "C" void kernel_launch(void* const* d_in, const int* in_sizes, int n_in,
                              void* d_out, int out_size, void* d_ws,
                              size_t ws_size, hipStream_t stream) {
  const int* h_ids = (const int*)d_in[0];
  const int* r_ids = (const int*)d_in[1];
  const float* ent = (const float*)d_in[2];
  const float* rel = (const float*)d_in[3];
  float* out = (float*)d_out;

  const int B = in_sizes[0];
  const int E = in_sizes[2] / DTOT;

  // ws layout: Ah table (16 KB) | Al table (16 KB, contiguous) | te2v | qrows
  bf16x8* ah_tab = (bf16x8*)d_ws;
  bf16x8* al_tab = ah_tab + 1024;
  float* te2v = (float*)((char*)d_ws + 32768);
  float* qrows = te2v + 256;  // 64*128 fp32 = 32 KB

  rie_translate<<<(B * 64 + 255) / 256, 256, 0, stream>>>(h_ids, r_ids, ent,
                                                          rel, qrows, te2v, B);
  rie_pack_frags<<<1, 256, 0, stream>>>(qrows, ah_tab, al_tab);

  const int ntiles = (E + 63) / 64;            // 64 entities per block-tile
  const int blocks = ntiles < 1280 ? ntiles : 1280;  // 5 blocks/CU x 256 CU
  rie_dist_mfma<<<blocks, 256, 0, stream>>>(ent, ah_tab, te2v, out, E, ntiles);
}

// Round 12
// 181.922 us; speedup vs baseline: 1.7153x; 1.7153x over previous
//
#include <hip/hip_runtime.h>
#include <math.h>

#define DHYP 64
#define DSPH 32
#define DEUC 32
#define DTOT 128
#define GAMMA_C 12.0f
#define EPS_C 1e-6f

typedef __attribute__((ext_vector_type(8))) __bf16 bf16x8;
typedef __attribute__((ext_vector_type(4))) float f32x4;

__device__ __forceinline__ float wsum64(float x) {
#pragma unroll
  for (int off = 1; off < 64; off <<= 1) x += __shfl_xor(x, off);
  return x;
}

// ---------------------------------------------------------------------------
// Kernel 1a: wave-per-row translate. Lane k holds dim k (hyperbolic) and
// dim 64+k (sphere for lanes 0..31, euclid for lanes 32..63).
// Emits plain fp32 q-rows (sign folded into q[0]) + te2v.
// ---------------------------------------------------------------------------
__global__ void rie_translate(const int* __restrict__ h_ids,
                              const int* __restrict__ r_ids,
                              const float* __restrict__ ent,
                              const float* __restrict__ rel,
                              float* __restrict__ qrows,
                              float* __restrict__ te2v, int B) {
  const int lane = threadIdx.x & 63;
  const int wave = threadIdx.x >> 6;
  const int b = blockIdx.x * (blockDim.x >> 6) + wave;
  if (b >= B) return;

  const float* __restrict__ h = ent + (long long)h_ids[b] * DTOT;
  const float* __restrict__ r = rel + (long long)r_ids[b] * DTOT;
  const float h1 = h[lane], h2 = h[64 + lane];
  const float r1 = r[lane], r2 = r[64 + lane];

  // ---- hyperbolic (dims 0..63; lane k = dim k) ----
  float ip = wsum64(lane == 0 ? -h1 * r1 : h1 * r1);  // minkowski(h,r)
  float v = fmaf(ip, h1, r1);                          // vh
  float mvv = wsum64(lane == 0 ? -v * v : v * v);      // minkowski(v,v)
  float vn = sqrtf(fmaxf(mvv, EPS_C));
  float ch = coshf(vn);
  float sh = sinhf(vn) / vn;
  float th = ch * h1 + sh * v;
  float q1 = (lane == 0) ? -th : th;  // fold Minkowski sign into query

  // ---- second half: sphere (lanes 0..31), euclid (lanes 32..63) ----
  const bool is_s = lane < 32;
  float ips = wsum64(is_s ? h2 * r2 : 0.0f);
  float vs = fmaf(-ips, h2, r2);
  float nv = wsum64(is_s ? vs * vs : 0.0f);
  float vns = fmaxf(sqrtf(nv), EPS_C);
  float cs = cosf(vns);
  float sn = sinf(vns) / vns;
  float ts = cs * h2 + sn * vs;

  float te = h2 + r2;
  float te2 = wsum64(is_s ? 0.0f : te * te);
  float q2 = is_s ? ts : te;

  qrows[b * DTOT + lane] = q1;
  qrows[b * DTOT + 64 + lane] = q2;
  if (lane == 0) te2v[b] = te2;
}

// ---------------------------------------------------------------------------
// Kernel 1b: repack q-rows into split-bf16 MFMA A-fragment tables.
// tab[(c*4+mt)*64 + g*16 + lmod] holds row (mt*16+lmod), k = 32c+8g..+8
// (m89-verified A layout); Al at +1024 entries (contiguous 32 KB total).
// ---------------------------------------------------------------------------
__global__ void rie_pack_frags(const float* __restrict__ qrows,
                               bf16x8* __restrict__ ah_tab,
                               bf16x8* __restrict__ al_tab) {
  const int t = threadIdx.x;
#pragma unroll
  for (int i = 0; i < 4; ++i) {
    const int idx = t + i * 256;
    const int cmt = idx >> 6;     // c*4 + mt
    const int c = cmt >> 2;
    const int mt = cmt & 3;
    const int lane = idx & 63;
    const int lmod = lane & 15;
    const int g = lane >> 4;
    const int row = mt * 16 + lmod;
    const int k0 = 32 * c + 8 * g;
    const float* __restrict__ src = qrows + row * DTOT + k0;
    const f32x4 a = *reinterpret_cast<const f32x4*>(src);
    const f32x4 bb = *reinterpret_cast<const f32x4*>(src + 4);
    bf16x8 Ah, Al;
#pragma unroll
    for (int j = 0; j < 4; ++j) {
      float x = a[j];
      __bf16 hx = (__bf16)x;
      Ah[j] = hx;
      Al[j] = (__bf16)(x - (float)hx);
      float y = bb[j];
      __bf16 hy = (__bf16)y;
      Ah[j + 4] = hy;
      Al[j + 4] = (__bf16)(y - (float)hy);
    }
    ah_tab[idx] = Ah;
    al_tab[idx] = Al;
  }
}

// ---------------------------------------------------------------------------
// Fast transcendentals (abs err ~7e-5, threshold headroom ~0.19)
// ---------------------------------------------------------------------------
__device__ __forceinline__ float fast_acos(float x) {
  float ax = fabsf(x);
  float p = fmaf(ax, -0.0187293f, 0.0742610f);
  p = fmaf(p, ax, -0.2121144f);
  p = fmaf(p, ax, 1.5707288f);
  float r = sqrtf(fmaxf(1.0f - ax, 0.0f)) * p;
  return (x < 0.0f) ? (3.14159265358979f - r) : r;
}

__device__ __forceinline__ float fast_acosh(float x) {
  // x >= 1. fma(x,x,-1) keeps full product precision near x=1.
  float t = x + sqrtf(fmaxf(fmaf(x, x, -1.0f), 0.0f));
  return 0.69314718055995f * __log2f(t);
}

// ---------------------------------------------------------------------------
// Kernel 2: split-bf16 MFMA distance GEMM. One wave = 16 entities x 64 q,
// ONE tile per block (waves stay in lockstep via the post-fill barrier --
// this is load-bearing: waves 0+1 / 2+3 complete each 128 B output line
// together; free-running waves caused 5x write amplification in round 9).
// A-table staged in LDS (32 KB); accumulators individually named (rule #20).
// ---------------------------------------------------------------------------
__device__ __forceinline__ void split8(const f32x4& lo, const f32x4& hi,
                                       bf16x8& Bh, bf16x8& Bl) {
#pragma unroll
  for (int j = 0; j < 4; ++j) {
    float x = lo[j];
    __bf16 hx = (__bf16)x;
    Bh[j] = hx;
    Bl[j] = (__bf16)(x - (float)hx);
    float y = hi[j];
    __bf16 hy = (__bf16)y;
    Bh[j + 4] = hy;
    Bl[j + 4] = (__bf16)(y - (float)hy);
  }
}

__device__ __forceinline__ void mt_step(const bf16x8* tab_lds, int base,
                                        const bf16x8& Bh, const bf16x8& Bl,
                                        f32x4& acc) {
  bf16x8 Ah = tab_lds[base];          // ds_read_b128
  bf16x8 Al = tab_lds[base + 1024];   // ds_read_b128 (Al half)
  acc = __builtin_amdgcn_mfma_f32_16x16x32_bf16(Ah, Bh, acc, 0, 0, 0);
  acc = __builtin_amdgcn_mfma_f32_16x16x32_bf16(Al, Bh, acc, 0, 0, 0);
  acc = __builtin_amdgcn_mfma_f32_16x16x32_bf16(Ah, Bl, acc, 0, 0, 0);
}

__global__ __launch_bounds__(256, 4) void rie_dist_mfma(
    const float* __restrict__ ent, const bf16x8* __restrict__ ah_tab,
    const float* __restrict__ te2v, float* __restrict__ out, int E) {
  __shared__ bf16x8 tab_lds[2048];  // 32 KB: [0..1023]=Ah, [1024..2047]=Al

  const int lane = threadIdx.x & 63;
  const int wave = threadIdx.x >> 6;
  const int e0 = (blockIdx.x * 4 + wave) * 16;
  const int lmod = lane & 15;
  const int lgrp = lane >> 4;

  // ---- issue the 8 entity loads first (in flight during LDS fill) ----
  const float* __restrict__ erow =
      ent + (long long)(e0 + lmod) * DTOT + 8 * lgrp;
  f32x4 b0a = *reinterpret_cast<const f32x4*>(erow);
  f32x4 b0b = *reinterpret_cast<const f32x4*>(erow + 4);
  f32x4 b1a = *reinterpret_cast<const f32x4*>(erow + 32);
  f32x4 b1b = *reinterpret_cast<const f32x4*>(erow + 36);
  f32x4 b2a = *reinterpret_cast<const f32x4*>(erow + 64);
  f32x4 b2b = *reinterpret_cast<const f32x4*>(erow + 68);
  f32x4 b3a = *reinterpret_cast<const f32x4*>(erow + 96);
  f32x4 b3b = *reinterpret_cast<const f32x4*>(erow + 100);

  // ---- cooperative copy of the 32 KB A-table into LDS ----
#pragma unroll
  for (int j = 0; j < 8; ++j)
    tab_lds[threadIdx.x + j * 256] = ah_tab[threadIdx.x + j * 256];
  __syncthreads();

  // ---- |ee|^2 of this lane's entity ----
  float ee2 = 0.0f;
#pragma unroll
  for (int j = 0; j < 4; ++j) {
    ee2 = fmaf(b3a[j], b3a[j], ee2);
    ee2 = fmaf(b3b[j], b3b[j], ee2);
  }
  ee2 += __shfl_xor(ee2, 16);
  ee2 += __shfl_xor(ee2, 32);

  const f32x4 z = {0.f, 0.f, 0.f, 0.f};
  f32x4 aH0 = z, aH1 = z, aH2 = z, aH3 = z;
  f32x4 aS0 = z, aS1 = z, aS2 = z, aS3 = z;
  f32x4 aE0 = z, aE1 = z, aE2 = z, aE3 = z;

  {  // chunk 0 (k 0..31, hyperbolic)
    bf16x8 Bh, Bl;
    split8(b0a, b0b, Bh, Bl);
    mt_step(tab_lds, (0 * 4 + 0) * 64 + lane, Bh, Bl, aH0);
    mt_step(tab_lds, (0 * 4 + 1) * 64 + lane, Bh, Bl, aH1);
    mt_step(tab_lds, (0 * 4 + 2) * 64 + lane, Bh, Bl, aH2);
    mt_step(tab_lds, (0 * 4 + 3) * 64 + lane, Bh, Bl, aH3);
  }
  {  // chunk 1 (k 32..63, hyperbolic)
    bf16x8 Bh, Bl;
    split8(b1a, b1b, Bh, Bl);
    mt_step(tab_lds, (1 * 4 + 0) * 64 + lane, Bh, Bl, aH0);
    mt_step(tab_lds, (1 * 4 + 1) * 64 + lane, Bh, Bl, aH1);
    mt_step(tab_lds, (1 * 4 + 2) * 64 + lane, Bh, Bl, aH2);
    mt_step(tab_lds, (1 * 4 + 3) * 64 + lane, Bh, Bl, aH3);
  }
  {  // chunk 2 (k 64..95, sphere)
    bf16x8 Bh, Bl;
    split8(b2a, b2b, Bh, Bl);
    mt_step(tab_lds, (2 * 4 + 0) * 64 + lane, Bh, Bl, aS0);
    mt_step(tab_lds, (2 * 4 + 1) * 64 + lane, Bh, Bl, aS1);
    mt_step(tab_lds, (2 * 4 + 2) * 64 + lane, Bh, Bl, aS2);
    mt_step(tab_lds, (2 * 4 + 3) * 64 + lane, Bh, Bl, aS3);
  }
  {  // chunk 3 (k 96..127, euclid)
    bf16x8 Bh, Bl;
    split8(b3a, b3b, Bh, Bl);
    mt_step(tab_lds, (3 * 4 + 0) * 64 + lane, Bh, Bl, aE0);
    mt_step(tab_lds, (3 * 4 + 1) * 64 + lane, Bh, Bl, aE1);
    mt_step(tab_lds, (3 * 4 + 2) * 64 + lane, Bh, Bl, aE2);
    mt_step(tab_lds, (3 * 4 + 3) * 64 + lane, Bh, Bl, aE3);
  }

  // ---- epilogue: fast transcendentals + store ----
#define EPI(MT, AH, AS, AE)                                                   \
  {                                                                           \
    const f32x4 t2 =                                                          \
        *reinterpret_cast<const f32x4*>(te2v + MT * 16 + 4 * lgrp);           \
    _Pragma("unroll") for (int r = 0; r < 4; ++r) {                           \
      float x = fmaxf(-AH[r], 1.0f + EPS_C);                                  \
      float dh = fast_acosh(x);                                               \
      float yv = fminf(fmaxf(AS[r], -1.0f + EPS_C), 1.0f - EPS_C);            \
      float dsv = fast_acos(yv);                                              \
      float de2 = fmaxf(t2[r] + ee2 - 2.0f * AE[r], 0.0f);                    \
      float dist = sqrtf(fmaf(dh, dh, fmaf(dsv, dsv, de2 + EPS_C)));          \
      out[(long long)(MT * 16 + 4 * lgrp + r) * E + e0 + lmod] =              \
          GAMMA_C - dist;                                                     \
    }                                                                         \
  }
  EPI(0, aH0, aS0, aE0);
  EPI(1, aH1, aS1, aE1);
  EPI(2, aH2, aS2, aE2);
  EPI(3, aH3, aS3, aE3);
#undef EPI
}

// ---------------------------------------------------------------------------
extern "C" void kernel_launch(void* const* d_in, const int* in_sizes, int n_in,
                              void* d_out, int out_size, void* d_ws,
                              size_t ws_size, hipStream_t stream) {
  const int* h_ids = (const int*)d_in[0];
  const int* r_ids = (const int*)d_in[1];
  const float* ent = (const float*)d_in[2];
  const float* rel = (const float*)d_in[3];
  float* out = (float*)d_out;

  const int B = in_sizes[0];
  const int E = in_sizes[2] / DTOT;

  // ws layout: Ah table (16 KB) | Al table (16 KB, contiguous) | te2v | qrows
  bf16x8* ah_tab = (bf16x8*)d_ws;
  bf16x8* al_tab = ah_tab + 1024;
  float* te2v = (float*)((char*)d_ws + 32768);
  float* qrows = te2v + 256;  // 64*128 fp32 = 32 KB

  rie_translate<<<(B * 64 + 255) / 256, 256, 0, stream>>>(h_ids, r_ids, ent,
                                                          rel, qrows, te2v, B);
  rie_pack_frags<<<1, 256, 0, stream>>>(qrows, ah_tab, al_tab);

  const int blocks = (E + 63) / 64;  // one wave per 16 entities, 4 waves/block
  rie_dist_mfma<<<blocks, 256, 0, stream>>>(ent, ah_tab, te2v, out, E);
}